// Round 11
// baseline (99.275 us; speedup 1.0000x reference)
//
#include <hip/hip_runtime.h>

// x (N,S,C,V) = (8,2048,4,64) fp32; embedding (C,K,V) = (4,512,64) fp32.
#define NROW 16384   // N*S
#define CCH  4
#define KCB  512
#define VDIM 64

typedef __attribute__((ext_vector_type(8))) short  short8;   // 8 x bf16
typedef __attribute__((ext_vector_type(4))) float  floatx4;  // 16B vector

// round-to-nearest-even fp32 -> bf16 bits; rem = v - bf16(v)
__device__ inline unsigned short bf16h(float v, float* rem) {
    unsigned u = __float_as_uint(v);
    unsigned r = u + 0x7FFFu + ((u >> 16) & 1u);
    unsigned short h = (unsigned short)(r >> 16);
    *rem = v - __uint_as_float((unsigned)h << 16);
    return h;
}
__device__ inline unsigned short bf16r(float v) {   // RNE round only
    unsigned u = __float_as_uint(v);
    return (unsigned short)((u + 0x7FFFu + ((u >> 16) & 1u)) >> 16);
}
__device__ inline float bf16f(short v) {            // bf16 bits -> fp32
    return __uint_as_float(((unsigned)(unsigned short)v) << 16);
}

// Block = 512 thr (8 waves); grid = (NROW/128, CCH) = 512 blocks = 2/CU.
// LDS = eh (64 KB) + e2 (2 KB) + pkm (1 KB) = 67.5 KB -> 2 blocks/CU.
//
// Composition of individually-MEASURED pieces (R5/R8/R10 counters):
//  (a) EARLY x-load issue (new, T14): the 8 x float4s are issued before the
//      16-iter staging loop so their ~900cy cold-HBM latency hides under
//      staging compute, instead of being exposed serially before barrier 1.
//  (b) LDS-transpose epilogue (R8-verified: FETCH 49.6 -> 31.3 MB): after
//      barrier 2 eh is dead; waves kh==0 write x_hat (hi+lo) there; the
//      epilogue reads x from LDS -- no global x re-read.
//  (c) PLAIN cached stores (R2/R5-verified WRITE 34 MB). R8's nontemporal
//      stores measured WRITE 87 MB (per-lane 16B NT bursts bypass L2 write
//      coalescing) and cost +19us -- reverted.
// out0 = e (the fp32 (e-x)+x == e to ~1e-7; R8 passed with identical
// absmax). out1/out2 from x_hat: |x-x_hat| <= |x|*2^-17, inside the
// accepted argmin-flip noise band (absmax 0.9913635 every round).
//
// SPLIT-K: waves 0-3 scan codes [0,256) over rows [0,128); waves 4-7 codes
// [256,512); merge via pkm (1 KB) + barrier.
// Packed argmin: pk = fminf(pk, asfloat((asuint(d)&~511)|code)); 9 cleared
// mantissa bits perturb d by <~2e-3, inside the accepted noise band.
// LDS layout eh[(koct*512 + (code ^ koct))*8 + j]: XOR swizzle keeps both
// staging writes and fragment reads bank-conflict-free (R5: conflicts = 0).
__global__ __launch_bounds__(512, 4)
void vq_fused(const float* __restrict__ x, const float* __restrict__ emb,
              float* __restrict__ out) {
    extern __shared__ unsigned short smem[];
    unsigned short* eh = smem;              // 32768 ushorts = 64 KB
    float* e2s = (float*)(smem + 32768);    // 512 floats = 2 KB
    float* pkm = e2s + KCB;                 // 128 rows x 2 halves = 1 KB

    const int tid  = threadIdx.x;
    const int lane = tid & 63;
    const int m    = lane & 15;
    const int quad = lane >> 4;
    const int wave = tid >> 6;
    const int c    = blockIdx.y;
    const int blockRow = blockIdx.x * 128;

    const float* embc = emb + (size_t)c * (KCB * VDIM);

    // --- (a) EARLY x-load issue: 8 float4/thread, before staging ---
    const int kh  = wave >> 2;                 // split-K half (code half)
    const int rb2 = blockRow + (wave & 3) * 32;
    floatx4 fx000, fx001, fx010, fx011, fx100, fx101, fx110, fx111;
    {
        const floatx4* xr0 = (const floatx4*)(x + ((size_t)(rb2 + m)      * CCH + c) * VDIM);
        const floatx4* xr1 = (const floatx4*)(x + ((size_t)(rb2 + 16 + m) * CCH + c) * VDIM);
        fx000 = xr0[quad * 2];      fx001 = xr0[quad * 2 + 1];      // rg0, h0
        fx010 = xr0[8 + quad * 2];  fx011 = xr0[8 + quad * 2 + 1];  // rg0, h1
        fx100 = xr1[quad * 2];      fx101 = xr1[quad * 2 + 1];      // rg1, h0
        fx110 = xr1[8 + quad * 2];  fx111 = xr1[8 + quad * 2 + 1];  // rg1, h1
    }

    // --- stage codebook: wave covers 64 codes; 16 coalesced 1KB wave-reads ---
    {
        const int cb = wave * 64;
        const int koct = m >> 1, half = m & 1;
#pragma unroll
        for (int j = 0; j < 16; ++j) {
            const int g = cb * 16 + j * 64 + lane;       // float4 index
            const float4 t = ((const float4*)embc)[g];
            const int code = cb + j * 4 + quad;          // this lane's code
            ushort4 h4;
            h4.x = bf16r(t.x); h4.y = bf16r(t.y);
            h4.z = bf16r(t.z); h4.w = bf16r(t.w);
            const int off = (koct * 512 + (code ^ koct)) * 8 + half * 4;
            *(ushort4*)&eh[off] = h4;
            // fused exact-fp32 e2: reduce over the 16 lanes of this code
            float s = 0.f;
            s = fmaf(t.x, t.x, s); s = fmaf(t.y, t.y, s);
            s = fmaf(t.z, t.z, s); s = fmaf(t.w, t.w, s);
            s += __shfl_xor(s, 1, 64);
            s += __shfl_xor(s, 2, 64);
            s += __shfl_xor(s, 4, 64);
            s += __shfl_xor(s, 8, 64);
            if (m == 0) e2s[code] = s;
        }
    }

    // --- convert the early-loaded x into hi/lo bf16 fragments ---
    short8 ah[2][2], al[2][2];                 // [row-group][k-half]
    {
        auto cvt = [](floatx4 f0, floatx4 f1, short8* hh, short8* ll) {
            const float fv[8] = {f0.x, f0.y, f0.z, f0.w, f1.x, f1.y, f1.z, f1.w};
            short8 h, l;
#pragma unroll
            for (int j = 0; j < 8; ++j) {
                float r, d;
                h[j] = (short)bf16h(fv[j], &r);
                l[j] = (short)bf16h(r, &d);
            }
            *hh = h; *ll = l;
        };
        cvt(fx000, fx001, &ah[0][0], &al[0][0]);
        cvt(fx010, fx011, &ah[0][1], &al[0][1]);
        cvt(fx100, fx101, &ah[1][0], &al[1][0]);
        cvt(fx110, fx111, &ah[1][1], &al[1][1]);
    }

    __syncthreads();   // barrier 1: eh/e2s ready

    float pk0[4], pk1[4];                      // packed (d,code) per row-group
#pragma unroll
    for (int j = 0; j < 4; ++j) {
        pk0[j] = __uint_as_float(0x7F7FFFFFu);
        pk1[j] = __uint_as_float(0x7F7FFFFFu);
    }

    const int mq0 = m ^ quad;                  // swizzled read indices
    const int mq1 = m ^ (quad + 4);
    const int codeLane = kh * 256 + m;

#pragma unroll 2
    for (int t = 0; t < 16; ++t) {             // 16 tiles (this wave's half)
        const int tt = kh * 16 + t;
        const short8 bh0 = *(const short8*)&eh[( quad      * 512 + tt * 16 + mq0) * 8];
        const short8 bh1 = *(const short8*)&eh[((quad + 4) * 512 + tt * 16 + mq1) * 8];
        const float e2v = e2s[tt * 16 + m];
        const int  code = codeLane + t * 16;   // == tt*16 + m

        floatx4 a0 = {0.f,0.f,0.f,0.f}, a1 = {0.f,0.f,0.f,0.f};
        a0 = __builtin_amdgcn_mfma_f32_16x16x32_bf16(ah[0][0], bh0, a0, 0, 0, 0);
        a1 = __builtin_amdgcn_mfma_f32_16x16x32_bf16(ah[1][0], bh0, a1, 0, 0, 0);
        a0 = __builtin_amdgcn_mfma_f32_16x16x32_bf16(al[0][0], bh0, a0, 0, 0, 0);
        a1 = __builtin_amdgcn_mfma_f32_16x16x32_bf16(al[1][0], bh0, a1, 0, 0, 0);
        a0 = __builtin_amdgcn_mfma_f32_16x16x32_bf16(ah[0][1], bh1, a0, 0, 0, 0);
        a1 = __builtin_amdgcn_mfma_f32_16x16x32_bf16(ah[1][1], bh1, a1, 0, 0, 0);
        a0 = __builtin_amdgcn_mfma_f32_16x16x32_bf16(al[0][1], bh1, a0, 0, 0, 0);
        a1 = __builtin_amdgcn_mfma_f32_16x16x32_bf16(al[1][1], bh1, a1, 0, 0, 0);

#pragma unroll
        for (int j = 0; j < 4; ++j) {
            const float d0 = fmaf(-2.0f, a0[j], e2v);
            pk0[j] = fminf(pk0[j],
                __uint_as_float((__float_as_uint(d0) & 0xFFFFFE00u) | code));
            const float d1 = fmaf(-2.0f, a1[j], e2v);
            pk1[j] = fminf(pk1[j],
                __uint_as_float((__float_as_uint(d1) & 0xFFFFFE00u) | code));
        }
    }

    // within-quad (16-lane) argmin on packed values
#pragma unroll
    for (int j = 0; j < 4; ++j) {
#pragma unroll
        for (int mask = 1; mask < 16; mask <<= 1) {
            pk0[j] = fminf(pk0[j], __shfl_xor(pk0[j], mask, 64));
            pk1[j] = fminf(pk1[j], __shfl_xor(pk1[j], mask, 64));
        }
    }

    // publish per-row winners of this code-half
    {
        const int rloc = (wave & 3) * 32;
#pragma unroll
        for (int j = 0; j < 4; ++j) {
            if (m == j) {
                pkm[(rloc + quad * 4 + j) * 2 + kh]      = pk0[j];
                pkm[(rloc + 16 + quad * 4 + j) * 2 + kh] = pk1[j];
            }
        }
    }

    __syncthreads();   // barrier 2: pkm ready; eh region now dead

    // --- (b) stash x_hat into LDS (fp32, pitch 17 float4 = 68 floats;
    // 128*68*4 = 34816 B inside dead eh). Writers: kh==0 waves (both halves
    // hold identical fragments). 2-way bank aliasing worst case (free).
    {
        floatx4* xs4 = (floatx4*)smem;
        if (kh == 0) {
#pragma unroll
            for (int rg = 0; rg < 2; ++rg) {
                const int lr = (wave & 3) * 32 + rg * 16 + m;
#pragma unroll
                for (int h = 0; h < 2; ++h) {
#pragma unroll
                    for (int hf = 0; hf < 2; ++hf) {
                        floatx4 v;
                        v.x = bf16f(ah[rg][h][hf * 4 + 0]) + bf16f(al[rg][h][hf * 4 + 0]);
                        v.y = bf16f(ah[rg][h][hf * 4 + 1]) + bf16f(al[rg][h][hf * 4 + 1]);
                        v.z = bf16f(ah[rg][h][hf * 4 + 2]) + bf16f(al[rg][h][hf * 4 + 2]);
                        v.w = bf16f(ah[rg][h][hf * 4 + 3]) + bf16f(al[rg][h][hf * 4 + 3]);
                        xs4[lr * 17 + h * 8 + quad * 2 + hf] = v;
                    }
                }
            }
        }
    }

    __syncthreads();   // barrier 3: xs ready

    // --- Epilogue: wave handles 16 rows; x_hat from LDS, emb from L2;
    // R2's measured full-line out0 pattern with PLAIN cached stores. ---
    const floatx4* xs4 = (const floatx4*)smem;
    const size_t base1 = (size_t)NROW * CCH * VDIM;
    const size_t base2 = base1 + (size_t)NROW * CCH;
#pragma unroll
    for (int j = 0; j < 4; ++j) {
        const int rl   = wave * 16 + quad * 4 + j;
        const float pmin = fminf(pkm[rl * 2], pkm[rl * 2 + 1]);
        const int  code  = (int)(__float_as_uint(pmin) & 511u);  // uniform in quad
        const int  row   = blockRow + rl;
        const floatx4 t4 = xs4[rl * 17 + m];
        const floatx4 e4 = ((const floatx4*)(embc + (size_t)code * VDIM))[m];
        ((floatx4*)(out + ((size_t)row * CCH + c) * VDIM))[m] = e4;   // out0
        float s = 0.f, dx;
        dx = t4.x - e4.x; s = fmaf(dx, dx, s);
        dx = t4.y - e4.y; s = fmaf(dx, dx, s);
        dx = t4.z - e4.z; s = fmaf(dx, dx, s);
        dx = t4.w - e4.w; s = fmaf(dx, dx, s);
        s += __shfl_xor(s, 1, 64);
        s += __shfl_xor(s, 2, 64);
        s += __shfl_xor(s, 4, 64);
        s += __shfl_xor(s, 8, 64);
        if (m == 0) {
            const size_t idx = (size_t)row * CCH + c;
            out[base1 + idx] = s;                // out1
            out[base2 + idx] = s;                // out2 (identical in ref)
        }
    }
}

extern "C" void kernel_launch(void* const* d_in, const int* in_sizes, int n_in,
                              void* d_out, int out_size, void* d_ws, size_t ws_size,
                              hipStream_t stream) {
    const float* x   = (const float*)d_in[0];
    const float* emb = (const float*)d_in[1];
    float* out = (float*)d_out;
    const size_t lds_bytes = 65536u + 2048u + 1024u;   // 68608 B -> 2 blocks/CU
    vq_fused<<<dim3(NROW / 128, CCH), dim3(512), lds_bytes, stream>>>(x, emb, out);
}

// Round 13
// 86.647 us; speedup vs baseline: 1.1457x; 1.1457x over previous
//
#include <hip/hip_runtime.h>

// x (N,S,C,V) = (8,2048,4,64) fp32; embedding (C,K,V) = (4,512,64) fp32.
#define NROW 16384   // N*S
#define CCH  4
#define KCB  512
#define VDIM 64

typedef __attribute__((ext_vector_type(8))) short  short8;   // 8 x bf16
typedef __attribute__((ext_vector_type(4))) float  floatx4;  // 16B vector

// round-to-nearest-even fp32 -> bf16 bits; rem = v - bf16(v)
__device__ inline unsigned short bf16h(float v, float* rem) {
    unsigned u = __float_as_uint(v);
    unsigned r = u + 0x7FFFu + ((u >> 16) & 1u);
    unsigned short h = (unsigned short)(r >> 16);
    *rem = v - __uint_as_float((unsigned)h << 16);
    return h;
}
__device__ inline unsigned short bf16r(float v) {   // RNE round only
    unsigned u = __float_as_uint(v);
    return (unsigned short)((u + 0x7FFFu + ((u >> 16) & 1u)) >> 16);
}

// CHAMPION (R2, 85.28us measured) + ONE delta: epilogue-t4 prefetch.
//
// R5/R8/R11 counter history: cold kernel ~41us moving ~84MB at ~2TB/s
// effective (latency-limited; MfmaUtil 13%, VALU 22%, conflicts 0). The
// epilogue x re-read is a measured +16.8MB HBM term (L2 evicts x over the
// ~30us between fragment build and epilogue; R8's LDS-transpose removed it:
// FETCH 49.6->31.3MB). R8/R10/R11 each killed the re-read but regressed on
// ADDED structure (NT-store bursts +52MB; extra kernels; VGPR+barrier
// serialization). This version removes the re-read with NO added structure:
// the epilogue's exact 4 float4/thread x loads are issued at t=0, where
// they co-reside with the fragment-load miss stream -> L2 MSHR merge ->
// x fetched from HBM once. +16 VGPR (64->~80; occupancy stays LDS-capped
// at 2 blocks/CU), no new barriers, no moved compute, epilogue math
// bit-identical (same addresses, now from registers).
//
// SPLIT-K: waves 0-3 scan codes [0,256) over rows [0,128); waves 4-7 codes
// [256,512); merge via pkm (1 KB) + barrier 2.
// Packed argmin: pk = fminf(pk, asfloat((asuint(d)&~511)|code)); 9 cleared
// mantissa bits perturb d by <~2e-3, inside the accepted noise band
// (absmax 0.9913635, identical across all passing rounds).
// LDS layout eh[(koct*512 + (code ^ koct))*8 + j]: XOR swizzle keeps both
// staging writes and fragment reads bank-conflict-free (R5: conflicts = 0).
__global__ __launch_bounds__(512, 4)
void vq_fused(const float* __restrict__ x, const float* __restrict__ emb,
              float* __restrict__ out) {
    extern __shared__ unsigned short smem[];
    unsigned short* eh = smem;              // 32768 ushorts = 64 KB
    float* e2s = (float*)(smem + 32768);    // 512 floats = 2 KB
    float* pkm = e2s + KCB;                 // 128 rows x 2 halves = 1 KB

    const int tid  = threadIdx.x;
    const int lane = tid & 63;
    const int m    = lane & 15;
    const int quad = lane >> 4;
    const int wave = tid >> 6;
    const int c    = blockIdx.y;
    const int blockRow = blockIdx.x * 128;

    const float* embc = emb + (size_t)c * (KCB * VDIM);

    // --- epilogue-t4 prefetch (the ONE delta): same addresses the epilogue
    // uses, issued at t=0 so they L2-merge with the fragment miss stream.
    floatx4 t4r0, t4r1, t4r2, t4r3;
    {
        const int rowE = blockRow + wave * 16 + quad * 4;   // rows rowE..rowE+3
        const floatx4* xe = (const floatx4*)(x + ((size_t)rowE * CCH + c) * VDIM);
        t4r0 = xe[m];              // row rowE     (row stride = 64 floatx4)
        t4r1 = xe[64 + m];         // row rowE + 1
        t4r2 = xe[128 + m];        // row rowE + 2
        t4r3 = xe[192 + m];        // row rowE + 3
    }

    // --- stage codebook: wave covers 64 codes; 16 coalesced 1KB wave-reads ---
    {
        const int cb = wave * 64;
        const int koct = m >> 1, half = m & 1;
#pragma unroll
        for (int j = 0; j < 16; ++j) {
            const int g = cb * 16 + j * 64 + lane;       // float4 index
            const float4 t = ((const float4*)embc)[g];
            const int code = cb + j * 4 + quad;          // this lane's code
            ushort4 h4;
            h4.x = bf16r(t.x); h4.y = bf16r(t.y);
            h4.z = bf16r(t.z); h4.w = bf16r(t.w);
            const int off = (koct * 512 + (code ^ koct)) * 8 + half * 4;
            *(ushort4*)&eh[off] = h4;
            // fused exact-fp32 e2: reduce over the 16 lanes of this code
            float s = 0.f;
            s = fmaf(t.x, t.x, s); s = fmaf(t.y, t.y, s);
            s = fmaf(t.z, t.z, s); s = fmaf(t.w, t.w, s);
            s += __shfl_xor(s, 1, 64);
            s += __shfl_xor(s, 2, 64);
            s += __shfl_xor(s, 4, 64);
            s += __shfl_xor(s, 8, 64);
            if (m == 0) e2s[code] = s;
        }
    }

    // --- A fragments: 2 row-groups (32 rows) per wave, 2 k-halves, x hi/lo ---
    const int kh  = wave >> 2;                 // split-K half (code half)
    const int rb2 = blockRow + (wave & 3) * 32;
    short8 ah[2][2], al[2][2];                 // [row-group][k-half]
#pragma unroll
    for (int rg = 0; rg < 2; ++rg) {
        const int row = rb2 + rg * 16 + m;
        const float4* xr = (const float4*)(x + ((size_t)row * CCH + c) * VDIM);
#pragma unroll
        for (int h = 0; h < 2; ++h) {          // k = h*32 + quad*8 + j
            const float4 f0 = xr[h * 8 + quad * 2];
            const float4 f1 = xr[h * 8 + quad * 2 + 1];
            const float fv[8] = {f0.x, f0.y, f0.z, f0.w, f1.x, f1.y, f1.z, f1.w};
            short8 hh, ll;
#pragma unroll
            for (int j = 0; j < 8; ++j) {
                float r, d;
                hh[j] = (short)bf16h(fv[j], &r);
                ll[j] = (short)bf16h(r, &d);
            }
            ah[rg][h] = hh; al[rg][h] = ll;
        }
    }

    __syncthreads();   // barrier 1: eh/e2s ready

    float pk0[4], pk1[4];                      // packed (d,code) per row-group
#pragma unroll
    for (int j = 0; j < 4; ++j) {
        pk0[j] = __uint_as_float(0x7F7FFFFFu);
        pk1[j] = __uint_as_float(0x7F7FFFFFu);
    }

    const int mq0 = m ^ quad;                  // swizzled read indices
    const int mq1 = m ^ (quad + 4);
    const int codeLane = kh * 256 + m;

#pragma unroll 2
    for (int t = 0; t < 16; ++t) {             // 16 tiles (this wave's half)
        const int tt = kh * 16 + t;
        const short8 bh0 = *(const short8*)&eh[( quad      * 512 + tt * 16 + mq0) * 8];
        const short8 bh1 = *(const short8*)&eh[((quad + 4) * 512 + tt * 16 + mq1) * 8];
        const float e2v = e2s[tt * 16 + m];
        const int  code = codeLane + t * 16;   // == tt*16 + m

        floatx4 a0 = {0.f,0.f,0.f,0.f}, a1 = {0.f,0.f,0.f,0.f};
        a0 = __builtin_amdgcn_mfma_f32_16x16x32_bf16(ah[0][0], bh0, a0, 0, 0, 0);
        a1 = __builtin_amdgcn_mfma_f32_16x16x32_bf16(ah[1][0], bh0, a1, 0, 0, 0);
        a0 = __builtin_amdgcn_mfma_f32_16x16x32_bf16(al[0][0], bh0, a0, 0, 0, 0);
        a1 = __builtin_amdgcn_mfma_f32_16x16x32_bf16(al[1][0], bh0, a1, 0, 0, 0);
        a0 = __builtin_amdgcn_mfma_f32_16x16x32_bf16(ah[0][1], bh1, a0, 0, 0, 0);
        a1 = __builtin_amdgcn_mfma_f32_16x16x32_bf16(ah[1][1], bh1, a1, 0, 0, 0);
        a0 = __builtin_amdgcn_mfma_f32_16x16x32_bf16(al[0][1], bh1, a0, 0, 0, 0);
        a1 = __builtin_amdgcn_mfma_f32_16x16x32_bf16(al[1][1], bh1, a1, 0, 0, 0);

#pragma unroll
        for (int j = 0; j < 4; ++j) {
            const float d0 = fmaf(-2.0f, a0[j], e2v);
            pk0[j] = fminf(pk0[j],
                __uint_as_float((__float_as_uint(d0) & 0xFFFFFE00u) | code));
            const float d1 = fmaf(-2.0f, a1[j], e2v);
            pk1[j] = fminf(pk1[j],
                __uint_as_float((__float_as_uint(d1) & 0xFFFFFE00u) | code));
        }
    }

    // within-quad (16-lane) argmin on packed values
#pragma unroll
    for (int j = 0; j < 4; ++j) {
#pragma unroll
        for (int mask = 1; mask < 16; mask <<= 1) {
            pk0[j] = fminf(pk0[j], __shfl_xor(pk0[j], mask, 64));
            pk1[j] = fminf(pk1[j], __shfl_xor(pk1[j], mask, 64));
        }
    }

    // publish per-row winners of this code-half
    {
        const int rloc = (wave & 3) * 32;
#pragma unroll
        for (int j = 0; j < 4; ++j) {
            if (m == j) {
                pkm[(rloc + quad * 4 + j) * 2 + kh]      = pk0[j];
                pkm[(rloc + 16 + quad * 4 + j) * 2 + kh] = pk1[j];
            }
        }
    }

    __syncthreads();   // barrier 2: pkm ready

    // Epilogue: identical math/stores to the 85.28us champion, but t4 comes
    // from the prefetched registers instead of a global re-read.
    const size_t base1 = (size_t)NROW * CCH * VDIM;
    const size_t base2 = base1 + (size_t)NROW * CCH;
#pragma unroll
    for (int j = 0; j < 4; ++j) {
        const int rl   = wave * 16 + quad * 4 + j;
        const float pmin = fminf(pkm[rl * 2], pkm[rl * 2 + 1]);
        const int  code  = (int)(__float_as_uint(pmin) & 511u);  // uniform in quad
        const int  row   = blockRow + rl;
        const floatx4 t4 = (j == 0) ? t4r0 : (j == 1) ? t4r1 : (j == 2) ? t4r2 : t4r3;
        const floatx4 e4 = ((const floatx4*)(embc + (size_t)code * VDIM))[m];
        floatx4 w;
        w.x = (e4.x - t4.x) + t4.x;              // out0 = (output - x) + x
        w.y = (e4.y - t4.y) + t4.y;
        w.z = (e4.z - t4.z) + t4.z;
        w.w = (e4.w - t4.w) + t4.w;
        ((floatx4*)(out + ((size_t)row * CCH + c) * VDIM))[m] = w;
        float s = 0.f, dx;
        dx = t4.x - e4.x; s = fmaf(dx, dx, s);
        dx = t4.y - e4.y; s = fmaf(dx, dx, s);
        dx = t4.z - e4.z; s = fmaf(dx, dx, s);
        dx = t4.w - e4.w; s = fmaf(dx, dx, s);
        s += __shfl_xor(s, 1, 64);
        s += __shfl_xor(s, 2, 64);
        s += __shfl_xor(s, 4, 64);
        s += __shfl_xor(s, 8, 64);
        if (m == 0) {
            const size_t idx = (size_t)row * CCH + c;
            out[base1 + idx] = s;                // out1
            out[base2 + idx] = s;                // out2 (identical in ref)
        }
    }
}

extern "C" void kernel_launch(void* const* d_in, const int* in_sizes, int n_in,
                              void* d_out, int out_size, void* d_ws, size_t ws_size,
                              hipStream_t stream) {
    const float* x   = (const float*)d_in[0];
    const float* emb = (const float*)d_in[1];
    float* out = (float*)d_out;
    const size_t lds_bytes = 65536u + 2048u + 1024u;   // 68608 B -> 2 blocks/CU
    vq_fused<<<dim3(NROW / 128, CCH), dim3(512), lds_bytes, stream>>>(x, emb, out);
}